// Round 2
// baseline (608.479 us; speedup 1.0000x reference)
//
#include <hip/hip_runtime.h>
#include <hip/hip_bf16.h>

// Problem constants (fixed shapes from the reference)
#define M_ROWS 25088   // 8 * 3136 embedding rows
#define N_CENT 4096    // centroids
#define K_DIM  1536    // feature dim
#define TILE   128
#define BK     32

typedef __attribute__((ext_vector_type(8))) short short8;     // 8 x bf16 (4 VGPRs)
typedef __attribute__((ext_vector_type(4))) float floatx4;    // MFMA accumulator

typedef __attribute__((address_space(1))) const void gvoid;
typedef __attribute__((address_space(3))) void lvoid;

__device__ __forceinline__ void load_lds16(const void* g, void* l) {
    // async global->LDS, 16B per lane; LDS dest = wave-uniform base + lane*16
    __builtin_amdgcn_global_load_lds((gvoid*)g, (lvoid*)l, 16, 0, 0);
}

// One block per row: fp32 -> bf16 convert + fp32 sum-of-squares.
// 384 threads * float4 = 1536 elements.
__global__ __launch_bounds__(384) void convert_rows(
    const float* __restrict__ src, __hip_bfloat16* __restrict__ dst,
    float* __restrict__ norms, unsigned int* __restrict__ minbuf)
{
    const int row = blockIdx.x;
    const int t = threadIdx.x;
    const float4 v = ((const float4*)(src + (size_t)row * K_DIM))[t];
    float s = v.x * v.x + v.y * v.y + v.z * v.z + v.w * v.w;

    union { __hip_bfloat16 h[4]; uint2 u; } pk;
    pk.h[0] = __float2bfloat16(v.x);
    pk.h[1] = __float2bfloat16(v.y);
    pk.h[2] = __float2bfloat16(v.z);
    pk.h[3] = __float2bfloat16(v.w);
    ((uint2*)(dst + (size_t)row * K_DIM))[t] = pk.u;

    // reduce sum-of-squares over 6 waves
    #pragma unroll
    for (int off = 32; off >= 1; off >>= 1) s += __shfl_down(s, off, 64);
    __shared__ float red[6];
    if ((t & 63) == 0) red[t >> 6] = s;
    __syncthreads();
    if (t == 0) {
        norms[row] = red[0] + red[1] + red[2] + red[3] + red[4] + red[5];
        if (minbuf) minbuf[row] = 0x7F800000u;  // +inf bits (ws is poisoned each launch)
    }
}

// 128x128 bf16 MFMA GEMM tile with fused per-row min(dist^2) epilogue.
// A = embeds [M,K] bf16, B = centroids [N,K] bf16 (NT layout -> both frag
// loads are contiguous ds_read_b128).
__global__ __launch_bounds__(256, 2) void gemm_min(
    const __hip_bfloat16* __restrict__ A,
    const __hip_bfloat16* __restrict__ B,
    const float* __restrict__ nx,
    const float* __restrict__ nc,
    unsigned int* __restrict__ minbuf)
{
    __shared__ __hip_bfloat16 sA[TILE * BK];   // row-major [128][32], no pad (global_load_lds layout)
    __shared__ __hip_bfloat16 sB[TILE * BK];

    const int tid  = threadIdx.x;
    const int wave = tid >> 6;
    const int lane = tid & 63;
    const int quad = lane >> 4;
    const int l15  = lane & 15;
    const int tile_n = blockIdx.x * TILE;
    const int tile_m = blockIdx.y * TILE;

    // staging geometry: one global_load_lds = 64 lanes x 16 B = 16 rows x 32 cols.
    // Round r (r=0,1), wave w covers LDS rows (r*4+w)*16 .. +16, i.e. bytes
    // [(r*4+w)*1024, +1024); lane l -> row r*64 + w*16 + l/4, cols (l%4)*8..+8.
    // 2 rounds x 4 waves = 8 loads = the full 128x32 tile (8 KB). (R1 bug:
    // r=0..3 wrote 16 KB, clobbering sB with out-of-tile A rows.)
    const int r4 = lane >> 2;
    const int c8 = (lane & 3) * 8;
    const __hip_bfloat16* aSrc = A + (size_t)(tile_m + wave * 16 + r4) * K_DIM + c8;
    const __hip_bfloat16* bSrc = B + (size_t)(tile_n + wave * 16 + r4) * K_DIM + c8;

    floatx4 acc[4][4];
    #pragma unroll
    for (int i = 0; i < 4; ++i)
        #pragma unroll
        for (int j = 0; j < 4; ++j)
            acc[i][j] = (floatx4){0.f, 0.f, 0.f, 0.f};

    const int wm = (wave >> 1) * 64;   // wave quadrant within 128x128
    const int wn = (wave & 1) * 64;

    const short* sAs = (const short*)sA;
    const short* sBs = (const short*)sB;

    for (int k0 = 0; k0 < K_DIM; k0 += BK) {
        #pragma unroll
        for (int r = 0; r < 2; ++r) {
            load_lds16(aSrc + (size_t)(r * 64) * K_DIM, (char*)sA + (r * 4 + wave) * 1024);
            load_lds16(bSrc + (size_t)(r * 64) * K_DIM, (char*)sB + (r * 4 + wave) * 1024);
        }
        __syncthreads();   // drains vmcnt -> tiles visible

        short8 a[4], b[4];
        #pragma unroll
        for (int im = 0; im < 4; ++im)
            a[im] = *(const short8*)&sAs[(wm + im * 16 + l15) * BK + quad * 8];
        #pragma unroll
        for (int in = 0; in < 4; ++in)
            b[in] = *(const short8*)&sBs[(wn + in * 16 + l15) * BK + quad * 8];

        #pragma unroll
        for (int im = 0; im < 4; ++im)
            #pragma unroll
            for (int in = 0; in < 4; ++in)
                acc[im][in] = __builtin_amdgcn_mfma_f32_16x16x32_bf16(
                    a[im], b[in], acc[im][in], 0, 0, 0);

        __syncthreads();   // all waves done reading before next overwrite
        aSrc += BK;
        bSrc += BK;
    }

    // Epilogue: dist^2 = nx[m] + nc[p] - 2*dot. Per-row min over this block's
    // 128 columns, then one atomicMin (positive-float uint bits) per row.
    float cn[4];
    #pragma unroll
    for (int in = 0; in < 4; ++in) cn[in] = nc[tile_n + wn + in * 16 + l15];

    #pragma unroll
    for (int im = 0; im < 4; ++im) {
        #pragma unroll
        for (int i = 0; i < 4; ++i) {
            // C/D layout: row = quad*4 + i, col = l15 (within 16x16 tile)
            float v =        cn[0] - 2.f * acc[im][0][i];
            v = fminf(v, cn[1] - 2.f * acc[im][1][i]);
            v = fminf(v, cn[2] - 2.f * acc[im][2][i]);
            v = fminf(v, cn[3] - 2.f * acc[im][3][i]);
            // min across the 16 lanes sharing this output row
            v = fminf(v, __shfl_xor(v, 8, 16));
            v = fminf(v, __shfl_xor(v, 4, 16));
            v = fminf(v, __shfl_xor(v, 2, 16));
            v = fminf(v, __shfl_xor(v, 1, 16));
            if (l15 == 0) {
                const int r = tile_m + wm + im * 16 + quad * 4 + i;
                atomicMin(&minbuf[r], __float_as_uint(v + nx[r]));
            }
        }
    }
}

__global__ void finalize_kernel(const unsigned int* __restrict__ minbuf,
                                float* __restrict__ out)
{
    const int i = blockIdx.x * 256 + threadIdx.x;
    if (i == 0) out[0] = 0.0f;                 // loss (eval mode)
    if (i < M_ROWS) out[1 + i] = sqrtf(__uint_as_float(minbuf[i]));
}

extern "C" void kernel_launch(void* const* d_in, const int* in_sizes, int n_in,
                              void* d_out, int out_size, void* d_ws, size_t ws_size,
                              hipStream_t stream)
{
    const float* embeds = (const float*)d_in[0];   // [8, 3136, 1536] fp32
    const float* cents  = (const float*)d_in[1];   // [4096, 1536] fp32
    float* out = (float*)d_out;                    // [1 + 25088] fp32

    char* ws = (char*)d_ws;
    const size_t offA   = 0;                               // 77,070,336 B
    const size_t offB   = offA + (size_t)M_ROWS * K_DIM * 2;   // 12,582,912 B
    const size_t offNx  = offB + (size_t)N_CENT * K_DIM * 2;   // 100,352 B
    const size_t offNc  = offNx + (size_t)M_ROWS * 4;          // 16,384 B
    const size_t offMin = offNc + (size_t)N_CENT * 4;          // 100,352 B

    __hip_bfloat16* Abf = (__hip_bfloat16*)(ws + offA);
    __hip_bfloat16* Bbf = (__hip_bfloat16*)(ws + offB);
    float* nx = (float*)(ws + offNx);
    float* nc = (float*)(ws + offNc);
    unsigned int* minbuf = (unsigned int*)(ws + offMin);

    convert_rows<<<M_ROWS, 384, 0, stream>>>(embeds, Abf, nx, minbuf);
    convert_rows<<<N_CENT, 384, 0, stream>>>(cents, Bbf, nc, nullptr);

    dim3 grid(N_CENT / TILE, M_ROWS / TILE);   // x = column tiles (fast) for A-tile L2/LLC reuse
    gemm_min<<<grid, 256, 0, stream>>>(Abf, Bbf, nx, nc, minbuf);

    finalize_kernel<<<(M_ROWS + 255) / 256, 256, 0, stream>>>(minbuf, out);
}